// Round 14
// baseline (38.559 us; speedup 1.0000x reference)
//
#include <hip/hip_runtime.h>

// SmoothSkeletonDual: exp-domain, packed-FP32 (2 cols/lane) register-strip.
// T'_0 = exp2(-x*C1); T'_{j+1} = box3x3(T'_j) (unnormalized).
// term_j = clip(-C2*log2(T'_j(p) * sum_{3x3} 1/T'_{j+1}(q)), 0, 1)
// skel = sum_{j=0}^{10} term_j
//
// Tile 128x64 (output 104x40, halo 12), RPW=4, NW=16 (1024 thr).
// Grid 10x26x2 = 520 blocks = 2 blocks/CU -> 32 waves/CU (8/SIMD, max TLP):
// R13 (240 blocks, 3.75 waves/SIMD) was latency-bound at ~2.7x its issue
// floor. launch_bounds(1024,8) pins the 64-VGPR budget for co-residency.
// Waves 0-2 / 13-15 are box-only (no rcp/log). 1 barrier/iter.

#define HH 1024
#define WW 1024
#define NB 2
#define OTX 104
#define OTY 40
#define TW 128
#define TH 64             // RPW*NW
#define RPW 4
#define NW 16
#define HALO 12
#define GX 10             // ceil(1024/104)
#define GY 26             // ceil(1024/40)

constexpr float C1 = 28.85390081777927f;   // 1/(alpha*ln2)
constexpr float C2 = 0.03465735902799726f; // alpha*ln2

typedef float f32x2 __attribute__((ext_vector_type(2)));

__device__ __forceinline__ int mir(int i, int n) {
    return i < 0 ? -i : (i >= n ? 2 * n - 2 - i : i);
}
// lane i <- lane i-1 (WAVE_SHR1 0x138; lane 0 zero-filled)
__device__ __forceinline__ float nbrL(float v) {
    return __int_as_float(__builtin_amdgcn_update_dpp(
        0, __float_as_int(v), 0x138, 0xf, 0xf, true));
}
// lane i <- lane i+1 (WAVE_SHL1 0x130; lane 63 zero-filled)
__device__ __forceinline__ float nbrR(float v) {
    return __int_as_float(__builtin_amdgcn_update_dpp(
        0, __float_as_int(v), 0x130, 0xf, 0xf, true));
}

__device__ __forceinline__ f32x2 pk_add(f32x2 a, f32x2 b) {
    f32x2 d;
    asm("v_pk_add_f32 %0, %1, %2" : "=v"(d) : "v"(a), "v"(b));
    return d;
}
// d = a + swap(b):  d.lo = a.lo + b.hi ; d.hi = a.hi + b.lo
__device__ __forceinline__ f32x2 pk_add_swapB(f32x2 a, f32x2 b) {
    f32x2 d;
    asm("v_pk_add_f32 %0, %1, %2 op_sel:[0,1] op_sel_hi:[1,0]"
        : "=v"(d) : "v"(a), "v"(b));
    return d;
}
__device__ __forceinline__ f32x2 pk_mul(f32x2 a, f32x2 b) {
    f32x2 d;
    asm("v_pk_mul_f32 %0, %1, %2" : "=v"(d) : "v"(a), "v"(b));
    return d;
}

// 3-tap horizontal sum of the 128-col row: lane holds cols (2i, 2i+1).
__device__ __forceinline__ f32x2 hsum3p(f32x2 P) {
    f32x2 LR;
    LR.x = nbrL(P.y);                 // c(2i-1)
    LR.y = nbrR(P.x);                 // c(2i+2)
    f32x2 X = pk_add(LR, P);          // (L+lo, R+hi)
    return pk_add_swapB(X, P);        // (L+lo+hi, R+hi+lo)
}

__global__ __launch_bounds__(1024, 8) void skel_k(const float* __restrict__ x0,
                                                  float* __restrict__ out) {
    __shared__ f32x2 halo[2][NW][4][64];
    const int lane = threadIdx.x & 63;
    const int w    = threadIdx.x >> 6;
    const int tx = blockIdx.x, ty = blockIdx.y, b = blockIdx.z;
    const int gx0 = tx * OTX - HALO, gy0 = ty * OTY - HALO;
    const int r0 = w * RPW;          // first owned tile-row

    const float* src = x0 + (size_t)b * HH * WW;

    // owned rows (f32x2), named scalars
    f32x2 a0, a1, a2, a3;
    const bool interior = (gx0 >= 0) && (gx0 + TW <= WW) &&
                          (gy0 >= 0) && (gy0 + TH <= HH);
    if (interior) {
        const float* base = src + (size_t)(gy0 + r0) * WW + gx0 + 2 * lane;
#define LOADROW(I, AV) { f32x2 v_ = *reinterpret_cast<const f32x2*>(base + (size_t)(I) * WW); \
        AV.x = __builtin_amdgcn_exp2f(v_.x * -C1); \
        AV.y = __builtin_amdgcn_exp2f(v_.y * -C1); }
        LOADROW(0, a0) LOADROW(1, a1) LOADROW(2, a2) LOADROW(3, a3)
#undef LOADROW
    } else {
        const int mx0 = mir(gx0 + 2 * lane, WW);
        const int mx1 = mir(gx0 + 2 * lane + 1, WW);
#define LOADROW(I, AV) { int my_ = mir(gy0 + r0 + (I), HH); \
        const float* rr_ = src + (size_t)my_ * WW; \
        AV.x = __builtin_amdgcn_exp2f(rr_[mx0] * -C1); \
        AV.y = __builtin_amdgcn_exp2f(rr_[mx1] * -C1); }
        LOADROW(0, a0) LOADROW(1, a1) LOADROW(2, a2) LOADROW(3, a3)
#undef LOADROW
    }

    f32x2 s0 = {0.f, 0.f}, s1 = s0, s2 = s0, s3 = s0;

    // wave-uniform: does this wave own any term rows ([12, 52))?
    const bool hasTerm = (r0 + RPW - 1 >= HALO) && (r0 < TH - HALO);
#define OKT(I) ((r0 + (I) >= HALO) && (r0 + (I) < TH - HALO))
    const bool ok0 = OKT(0), ok1 = OKT(1), ok2 = OKT(2), ok3 = OKT(3);
#undef OKT

    #pragma unroll 1
    for (int j = 0; j < 11; ++j) {
        const int p = j & 1;
        halo[p][w][0][lane] = a0;
        halo[p][w][1][lane] = a1;
        halo[p][w][2][lane] = a2;   // RPW-2
        halo[p][w][3][lane] = a3;   // RPW-1
        __syncthreads();
        f32x2 one2 = {1.f, 1.f};
        f32x2 hm2 = (w > 0)      ? halo[p][w - 1][2][lane] : one2;  // O[-2]
        f32x2 hm1 = (w > 0)      ? halo[p][w - 1][3][lane] : one2;  // O[-1]
        f32x2 hp0 = (w < NW - 1) ? halo[p][w + 1][0][lane] : one2;  // O[4]
        f32x2 hp1 = (w < NW - 1) ? halo[p][w + 1][1][lane] : one2;  // O[5]

        f32x2 h_m = hsum3p(hm2);
        f32x2 h_c = hsum3p(hm1);
        f32x2 n_prev = {0.f, 0.f};

        if (hasTerm) {
            f32x2 r_2 = {0.f, 0.f}, r_1 = r_2;
#define STEPC(OP1) \
            f32x2 h_p = hsum3p(OP1); \
            f32x2 n   = pk_add(pk_add(h_m, h_c), h_p); \
            f32x2 rc; rc.x = __builtin_amdgcn_rcpf(n.x); \
                      rc.y = __builtin_amdgcn_rcpf(n.y); \
            f32x2 r_0 = hsum3p(rc);
#define STEP0(OP1) { STEPC(OP1) \
            n_prev = n; h_m = h_c; h_c = h_p; r_2 = r_1; r_1 = r_0; }
#define STEP(OP1, AT, ST, OKb) { STEPC(OP1) \
            if (OKb) { \
                f32x2 rs = pk_add(pk_add(r_2, r_1), r_0); \
                f32x2 PS = pk_mul(AT, rs); \
                f32x2 t; \
                t.x = __builtin_amdgcn_fmed3f(-C2 * __builtin_amdgcn_logf(PS.x), 0.f, 1.f); \
                t.y = __builtin_amdgcn_fmed3f(-C2 * __builtin_amdgcn_logf(PS.y), 0.f, 1.f); \
                ST = pk_add(ST, t); \
            } \
            AT = n_prev; \
            n_prev = n; h_m = h_c; h_c = h_p; r_2 = r_1; r_1 = r_0; }

            STEP0(a0)                  // k=-1
            STEP0(a1)                  // k=0
            STEP(a2,  a0, s0, ok0)     // k=1
            STEP(a3,  a1, s1, ok1)
            STEP(hp0, a2, s2, ok2)
            STEP(hp1, a3, s3, ok3)     // k=4
#undef STEP
#undef STEP0
#undef STEPC
        } else {
            // box-only sweep (no term rows)
#define BSTEP0(OP1) { f32x2 h_p = hsum3p(OP1); \
            f32x2 n = pk_add(pk_add(h_m, h_c), h_p); \
            n_prev = n; h_m = h_c; h_c = h_p; }
#define BSTEP(OP1, AT) { f32x2 h_p = hsum3p(OP1); \
            f32x2 n = pk_add(pk_add(h_m, h_c), h_p); \
            AT = n_prev; n_prev = n; h_m = h_c; h_c = h_p; }
            BSTEP0(a0)
            BSTEP0(a1)
            BSTEP(a2,  a0)
            BSTEP(a3,  a1)
            BSTEP(hp0, a2)
            BSTEP(hp1, a3)
#undef BSTEP
#undef BSTEP0
        }
        // no trailing barrier: parity buffer + next iter's barrier suffice
    }

    // store output: lanes 6..57 (tile cols [12,116)), rows [12, 52)
    if (hasTerm && lane >= 6 && lane <= 57) {
        int gx = gx0 + 2 * lane;
        if (gx >= 0 && gx + 1 < WW) {
            float* dst = out + (size_t)b * HH * WW;
#define STOREROW(I, SV) { int trow = r0 + (I); \
            if (trow >= HALO && trow < TH - HALO) { \
                int gy = gy0 + trow; \
                if (gy < HH) \
                    *reinterpret_cast<f32x2*>(&dst[(size_t)gy * WW + gx]) = SV; } }
            STOREROW(0, s0) STOREROW(1, s1) STOREROW(2, s2) STOREROW(3, s3)
#undef STOREROW
        }
    }
}

extern "C" void kernel_launch(void* const* d_in, const int* in_sizes, int n_in,
                              void* d_out, int out_size, void* d_ws, size_t ws_size,
                              hipStream_t stream) {
    const float* x0 = (const float*)d_in[0];
    float* skel = (float*)d_out;
    skel_k<<<dim3(GX, GY, NB), dim3(1024, 1, 1), 0, stream>>>(x0, skel);
}

// Round 15
// 29.142 us; speedup vs baseline: 1.3231x; 1.3231x over previous
//
#include <hip/hip_runtime.h>

// SmoothSkeletonDual: exp-domain, packed-FP32 register-strip, uneven strips.
// T'_0 = exp2(-x*C1); T'_{j+1} = box3x3(T'_j) (unnormalized).
// term_j = clip(-C2*log2(T'_j(p) * sum_{3x3} 1/T'_{j+1}(q)), 0, 1)
// skel = sum_{j=0}^{10} term_j
//
// Tile 128x112 (output 104x88, halo 12), grid 240 = 1 block/CU.
// 16 waves: w0 owns rows 0-11 (pure halo, BOX-ONLY sweep: no rcp/log),
// w15 rows 100-111 (box-only), w1-4 own 7 term rows each, w5-14 own 6.
// All term rows are in-window by construction -> no masks.
// Lane owns 2 adjacent cols (f32x2); NATIVE vector ops (clang emits
// v_pk_add_f32/v_pk_mul_f32 on gfx950) instead of inline asm.
// Horizontal neighbors: DPP wave shifts; vertical halo (2 rows/side) via
// parity-double-buffered LDS, 1 barrier/iter.

#define HH 1024
#define WW 1024
#define NB 2
#define OTX 104
#define OTY 88
#define TW 128
#define TH 112
#define NW 16
#define HALO 12
#define GX 10             // ceil(1024/104)
#define GY 12             // ceil(1024/88)

constexpr float C1 = 28.85390081777927f;   // 1/(alpha*ln2)
constexpr float C2 = 0.03465735902799726f; // alpha*ln2

typedef float f32x2 __attribute__((ext_vector_type(2)));

__device__ __forceinline__ int mir(int i, int n) {
    return i < 0 ? -i : (i >= n ? 2 * n - 2 - i : i);
}
// lane i <- lane i-1 (WAVE_SHR1 0x138; lane 0 zero-filled)
__device__ __forceinline__ float nbrL(float v) {
    return __int_as_float(__builtin_amdgcn_update_dpp(
        0, __float_as_int(v), 0x138, 0xf, 0xf, true));
}
// lane i <- lane i+1 (WAVE_SHL1 0x130; lane 63 zero-filled)
__device__ __forceinline__ float nbrR(float v) {
    return __int_as_float(__builtin_amdgcn_update_dpp(
        0, __float_as_int(v), 0x130, 0xf, 0xf, true));
}

// 3-tap horizontal sums: lane holds cols (2i, 2i+1).
// out.lo = c(2i-1)+c(2i)+c(2i+1); out.hi = c(2i)+c(2i+1)+c(2i+2).
__device__ __forceinline__ f32x2 hsum3p(f32x2 P) {
    float s = P.x + P.y;
    f32x2 LR;
    LR.x = nbrL(P.y) + s;
    LR.y = nbrR(P.x) + s;
    return LR;
}

__global__ __launch_bounds__(1024, 4) void skel_k(const float* __restrict__ x0,
                                                  float* __restrict__ out) {
    __shared__ f32x2 halo[2][NW][4][64];
    const int lane = threadIdx.x & 63;
    const int w    = threadIdx.x >> 6;
    const int tx = blockIdx.x, ty = blockIdx.y, b = blockIdx.z;
    const int gx0 = tx * OTX - HALO, gy0 = ty * OTY - HALO;
    // strip start row: w0:0(12 rows) w1-4:7 rows w5-14:6 rows w15:100(12)
    const int r0 = (w == 0) ? 0
                 : (w <= 4) ? 12 + 7 * (w - 1)
                 : (w <= 14) ? 40 + 6 * (w - 5) : 100;
    const bool isBox = (w == 0) || (w == 15);
    const bool is7   = (w >= 1) && (w <= 4);

    const float* src = x0 + (size_t)b * HH * WW;
    const bool interior = (gx0 >= 0) && (gx0 + TW <= WW) &&
                          (gy0 >= 0) && (gy0 + TH <= HH);
    const int mx0 = mir(gx0 + 2 * lane, WW);
    const int mx1 = mir(gx0 + 2 * lane + 1, WW);
    const float* base = src + (size_t)(gy0 + r0) * WW + gx0 + 2 * lane;

    f32x2 a0, a1, a2, a3, a4, a5, a6, a7, a8, a9, a10, a11;
#define LD(I, AV) { \
    if (interior) { \
        f32x2 v_ = *reinterpret_cast<const f32x2*>(base + (size_t)(I) * WW); \
        AV.x = __builtin_amdgcn_exp2f(v_.x * -C1); \
        AV.y = __builtin_amdgcn_exp2f(v_.y * -C1); \
    } else { \
        int my_ = mir(gy0 + r0 + (I), HH); \
        const float* rr_ = src + (size_t)my_ * WW; \
        AV.x = __builtin_amdgcn_exp2f(rr_[mx0] * -C1); \
        AV.y = __builtin_amdgcn_exp2f(rr_[mx1] * -C1); \
    } }
    LD(0, a0) LD(1, a1) LD(2, a2) LD(3, a3) LD(4, a4) LD(5, a5)
    if (isBox) { LD(6, a6) LD(7, a7) LD(8, a8) LD(9, a9) LD(10, a10) LD(11, a11) }
    else if (is7) { LD(6, a6) }
#undef LD

    f32x2 s0 = {0.f, 0.f}, s1 = s0, s2 = s0, s3 = s0, s4 = s0, s5 = s0, s6 = s0;

    #pragma unroll 1
    for (int j = 0; j < 11; ++j) {
        const int p = j & 1;
        f32x2 pub2, pub3;
        if (isBox)    { pub2 = a10; pub3 = a11; }
        else if (is7) { pub2 = a5;  pub3 = a6;  }
        else          { pub2 = a4;  pub3 = a5;  }
        halo[p][w][0][lane] = a0;
        halo[p][w][1][lane] = a1;
        halo[p][w][2][lane] = pub2;
        halo[p][w][3][lane] = pub3;
        __syncthreads();
        f32x2 one2 = {1.f, 1.f};
        f32x2 hm2 = (w > 0)      ? halo[p][w - 1][2][lane] : one2;  // O[-2]
        f32x2 hm1 = (w > 0)      ? halo[p][w - 1][3][lane] : one2;  // O[-1]
        f32x2 hp0 = (w < NW - 1) ? halo[p][w + 1][0][lane] : one2;  // O[RPW]
        f32x2 hp1 = (w < NW - 1) ? halo[p][w + 1][1][lane] : one2;  // O[RPW+1]

        f32x2 h_m = hsum3p(hm2);
        f32x2 h_c = hsum3p(hm1);
        f32x2 n_prev = {0.f, 0.f};

        if (!isBox) {
            f32x2 r_2 = {0.f, 0.f}, r_1 = r_2;
#define STEPC(OP1) \
            f32x2 h_p = hsum3p(OP1); \
            f32x2 n   = h_m + h_c + h_p; \
            f32x2 rc; rc.x = __builtin_amdgcn_rcpf(n.x); \
                      rc.y = __builtin_amdgcn_rcpf(n.y); \
            f32x2 r_0 = hsum3p(rc);
#define STEP0(OP1) { STEPC(OP1) \
            n_prev = n; h_m = h_c; h_c = h_p; r_2 = r_1; r_1 = r_0; }
#define STEP(OP1, AT, ST) { STEPC(OP1) \
            f32x2 PS = AT * (r_2 + r_1 + r_0); \
            f32x2 t; \
            t.x = __builtin_amdgcn_fmed3f(-C2 * __builtin_amdgcn_logf(PS.x), 0.f, 1.f); \
            t.y = __builtin_amdgcn_fmed3f(-C2 * __builtin_amdgcn_logf(PS.y), 0.f, 1.f); \
            ST += t; \
            AT = n_prev; \
            n_prev = n; h_m = h_c; h_c = h_p; r_2 = r_1; r_1 = r_0; }

            STEP0(a0)
            STEP0(a1)
            STEP(a2, a0, s0)
            STEP(a3, a1, s1)
            STEP(a4, a2, s2)
            STEP(a5, a3, s3)
            if (is7) {
                STEP(a6,  a4, s4)
                STEP(hp0, a5, s5)
                STEP(hp1, a6, s6)
            } else {
                STEP(hp0, a4, s4)
                STEP(hp1, a5, s5)
            }
#undef STEP
#undef STEP0
#undef STEPC
        } else {
            // box-only sweep: 12 rows, no rcp/log/term
#define BSTEP0(OP1) { f32x2 h_p = hsum3p(OP1); \
            f32x2 n = h_m + h_c + h_p; \
            n_prev = n; h_m = h_c; h_c = h_p; }
#define BSTEP(OP1, AT) { f32x2 h_p = hsum3p(OP1); \
            f32x2 n = h_m + h_c + h_p; \
            AT = n_prev; n_prev = n; h_m = h_c; h_c = h_p; }
            BSTEP0(a0)
            BSTEP0(a1)
            BSTEP(a2,  a0)
            BSTEP(a3,  a1)
            BSTEP(a4,  a2)
            BSTEP(a5,  a3)
            BSTEP(a6,  a4)
            BSTEP(a7,  a5)
            BSTEP(a8,  a6)
            BSTEP(a9,  a7)
            BSTEP(a10, a8)
            BSTEP(a11, a9)
            BSTEP(hp0, a10)
            BSTEP(hp1, a11)
#undef BSTEP
#undef BSTEP0
        }
        // no trailing barrier: parity buffer + next iter's barrier suffice
    }

    // store: term waves only; lanes 6..57 cover the 104 output cols
    if (!isBox && lane >= 6 && lane <= 57) {
        int gx = gx0 + 2 * lane;          // >= 0 since lane >= 6
        if (gx + 1 < WW) {
            float* dst = out + (size_t)b * HH * WW;
#define STORE(I, SV) { int gy = gy0 + r0 + (I); \
            if (gy < HH) \
                *reinterpret_cast<f32x2*>(&dst[(size_t)gy * WW + gx]) = SV; }
            STORE(0, s0) STORE(1, s1) STORE(2, s2) STORE(3, s3)
            STORE(4, s4) STORE(5, s5)
            if (is7) { STORE(6, s6) }
#undef STORE
        }
    }
}

extern "C" void kernel_launch(void* const* d_in, const int* in_sizes, int n_in,
                              void* d_out, int out_size, void* d_ws, size_t ws_size,
                              hipStream_t stream) {
    const float* x0 = (const float*)d_in[0];
    float* skel = (float*)d_out;
    skel_k<<<dim3(GX, GY, NB), dim3(1024, 1, 1), 0, stream>>>(x0, skel);
}